// Round 1
// baseline (11934.082 us; speedup 1.0000x reference)
//
#include <hip/hip_runtime.h>

#define N_NODES 100000
#define N_EDGES 3200000
#define N_GRAPHS 5000
#define BN_EPS 1e-5f

// h = x @ node_w + node_b   [N,14]@[14,32]
__global__ void k_encode(const float* __restrict__ x, const float* __restrict__ W,
                         const float* __restrict__ b, float* __restrict__ h) {
    __shared__ float sW[448];
    __shared__ float sb[32];
    for (int i = threadIdx.x; i < 448; i += 256) sW[i] = W[i];
    if (threadIdx.x < 32) sb[threadIdx.x] = b[threadIdx.x];
    __syncthreads();
    int n = blockIdx.x * 256 + threadIdx.x;
    if (n >= N_NODES) return;
    float xi[14];
#pragma unroll
    for (int k = 0; k < 14; k++) xi[k] = x[n * 14 + k];
    float4* hp = (float4*)(h + (size_t)n * 32);
#pragma unroll
    for (int q = 0; q < 8; q++) {
        float4 acc;
        float* ap = (float*)&acc;
#pragma unroll
        for (int i = 0; i < 4; i++) {
            int c = q * 4 + i;
            float a = sb[c];
#pragma unroll
            for (int k = 0; k < 14; k++) a += xi[k] * sW[k * 32 + c];
            ap[i] = a;
        }
        hp[q] = acc;
    }
}

// msg = relu(h[src] + (edge_attr@edge_w + edge_b)); agg[dst] += msg  (fused edge encoder)
__global__ void k_edge(const int* __restrict__ ei, const float* __restrict__ ea,
                       const float* __restrict__ eW, const float* __restrict__ eb,
                       const float* __restrict__ h, float* __restrict__ agg) {
    __shared__ float sW[96], sb[32];
    if (threadIdx.x < 96) sW[threadIdx.x] = eW[threadIdx.x];
    if (threadIdx.x < 32) sb[threadIdx.x] = eb[threadIdx.x];
    __syncthreads();
    int e = blockIdx.x * 256 + threadIdx.x;
    if (e >= N_EDGES) return;
    int src = ei[e];
    int dst = ei[N_EDGES + e];
    float a0 = ea[(size_t)e * 3 + 0], a1 = ea[(size_t)e * 3 + 1], a2 = ea[(size_t)e * 3 + 2];
    const float4* hs = (const float4*)(h + (size_t)src * 32);
    float* ad = agg + (size_t)dst * 32;
#pragma unroll
    for (int q = 0; q < 8; q++) {
        float4 hv = hs[q];
        float* hvp = (float*)&hv;
#pragma unroll
        for (int i = 0; i < 4; i++) {
            int c = q * 4 + i;
            float m = hvp[i] + a0 * sW[c] + a1 * sW[32 + c] + a2 * sW[64 + c] + sb[c];
            m = fmaxf(m, 0.f);
            atomicAdd(ad + c, m);
        }
    }
}

// z = relu((h+agg)@W1+b1)@W2+b2, written in-place over agg; accumulate per-channel sum/sumsq
__global__ void __launch_bounds__(256) k_update(const float* __restrict__ h, float* __restrict__ zio,
                                                const float* __restrict__ W1, const float* __restrict__ b1,
                                                const float* __restrict__ W2, const float* __restrict__ b2,
                                                float* __restrict__ stats) {
    __shared__ float sW1[2400], sW2[2400], sb1[75], sb2[32];
    for (int i = threadIdx.x; i < 2400; i += 256) { sW1[i] = W1[i]; sW2[i] = W2[i]; }
    if (threadIdx.x < 75) sb1[threadIdx.x] = b1[threadIdx.x];
    if (threadIdx.x < 32) sb2[threadIdx.x] = b2[threadIdx.x];
    __syncthreads();
    int n = blockIdx.x * 256 + threadIdx.x;
    bool valid = n < N_NODES;
    float zin[32];
    if (valid) {
#pragma unroll
        for (int c = 0; c < 32; c++) zin[c] = h[(size_t)n * 32 + c] + zio[(size_t)n * 32 + c];
    } else {
#pragma unroll
        for (int c = 0; c < 32; c++) zin[c] = 0.f;
    }
    float hid[75];
#pragma unroll
    for (int j = 0; j < 75; j++) hid[j] = sb1[j];
    for (int c = 0; c < 32; c++) {
        float zc = zin[c];
#pragma unroll
        for (int j = 0; j < 75; j++) hid[j] += zc * sW1[c * 75 + j];
    }
#pragma unroll
    for (int j = 0; j < 75; j++) hid[j] = fmaxf(hid[j], 0.f);
    float zo[32];
#pragma unroll
    for (int c = 0; c < 32; c++) zo[c] = sb2[c];
    for (int j = 0; j < 75; j++) {
        float hj = hid[j];
#pragma unroll
        for (int c = 0; c < 32; c++) zo[c] += hj * sW2[j * 32 + c];
    }
    if (valid) {
#pragma unroll
        for (int c = 0; c < 32; c++) zio[(size_t)n * 32 + c] = zo[c];
    }
    int lane = threadIdx.x & 63;
#pragma unroll
    for (int c = 0; c < 32; c++) {
        float s = valid ? zo[c] : 0.f;
        float s2 = valid ? zo[c] * zo[c] : 0.f;
#pragma unroll
        for (int off = 32; off > 0; off >>= 1) {
            s += __shfl_down(s, off, 64);
            s2 += __shfl_down(s2, off, 64);
        }
        if (lane == 0) { atomicAdd(&stats[c], s); atomicAdd(&stats[32 + c], s2); }
    }
}

// h = relu((z - mu) * g / sqrt(var+eps) + b); one float4 (4 channels) per thread
__global__ void k_bn(const float* __restrict__ z, float* __restrict__ h,
                     const float* __restrict__ stats, const float* __restrict__ g,
                     const float* __restrict__ b) {
    int t = blockIdx.x * 256 + threadIdx.x;
    if (t >= N_NODES * 8) return;
    int q = t & 7;
    float4 zv = ((const float4*)z)[t];
    float* zp = (float*)&zv;
    float4 ov;
    float* op = (float*)&ov;
    const float invN = 1.0f / (float)N_NODES;
#pragma unroll
    for (int i = 0; i < 4; i++) {
        int c = q * 4 + i;
        float mu = stats[c] * invN;
        float var = stats[32 + c] * invN - mu * mu;
        float sc = g[c] / sqrtf(var + BN_EPS);
        float val = (zp[i] - mu) * sc + b[c];
        op[i] = fmaxf(val, 0.f);
    }
    ((float4*)h)[t] = ov;
}

__global__ void k_pool(const float* __restrict__ h, const int* __restrict__ batch,
                       float* __restrict__ gsum, float* __restrict__ gcnt) {
    int t = blockIdx.x * 256 + threadIdx.x;
    if (t >= N_NODES * 8) return;
    int n = t >> 3, q = t & 7;
    int g = batch[n];
    float4 hv = ((const float4*)h)[t];
    float* hp = (float*)&hv;
    float* gp = gsum + (size_t)g * 32 + q * 4;
#pragma unroll
    for (int i = 0; i < 4; i++) atomicAdd(gp + i, hp[i]);
    if (q == 0) atomicAdd(&gcnt[g], 1.0f);
}

__global__ void k_head(const float* __restrict__ gsum, const float* __restrict__ gcnt,
                       const float* __restrict__ W1, const float* __restrict__ b1,
                       const float* __restrict__ W2, const float* __restrict__ b2,
                       float* __restrict__ out) {
    __shared__ float sW1[512], sb1[16], sW2[32], sb2[2];
    for (int i = threadIdx.x; i < 512; i += 256) sW1[i] = W1[i];
    if (threadIdx.x < 16) sb1[threadIdx.x] = b1[threadIdx.x];
    if (threadIdx.x < 32) sW2[threadIdx.x] = W2[threadIdx.x];
    if (threadIdx.x < 2) sb2[threadIdx.x] = b2[threadIdx.x];
    __syncthreads();
    int gI = blockIdx.x * 256 + threadIdx.x;
    if (gI >= N_GRAPHS) return;
    float cnt = fmaxf(gcnt[gI], 1.0f);
    float inv = 1.0f / cnt;
    float gx[32];
#pragma unroll
    for (int c = 0; c < 32; c++) gx[c] = gsum[(size_t)gI * 32 + c] * inv;
    float hid[16];
#pragma unroll
    for (int j = 0; j < 16; j++) {
        float a = sb1[j];
#pragma unroll
        for (int c = 0; c < 32; c++) a += gx[c] * sW1[c * 16 + j];
        hid[j] = fmaxf(a, 0.f);
    }
#pragma unroll
    for (int o = 0; o < 2; o++) {
        float a = sb2[o];
#pragma unroll
        for (int j = 0; j < 16; j++) a += hid[j] * sW2[j * 2 + o];
        out[(size_t)gI * 2 + o] = a;
    }
}

extern "C" void kernel_launch(void* const* d_in, const int* in_sizes, int n_in,
                              void* d_out, int out_size, void* d_ws, size_t ws_size,
                              hipStream_t stream) {
    const float* x       = (const float*)d_in[0];
    const int*   ei      = (const int*)d_in[1];
    const float* eattr   = (const float*)d_in[2];
    const int*   batch   = (const int*)d_in[3];
    const float* node_w  = (const float*)d_in[4];
    const float* node_b  = (const float*)d_in[5];
    const float* edge_w  = (const float*)d_in[6];
    const float* edge_b  = (const float*)d_in[7];
    const float* conv_w1 = (const float*)d_in[8];
    const float* conv_b1 = (const float*)d_in[9];
    const float* conv_w2 = (const float*)d_in[10];
    const float* conv_b2 = (const float*)d_in[11];
    const float* bn_g    = (const float*)d_in[12];
    const float* bn_b    = (const float*)d_in[13];
    const float* lin1_w  = (const float*)d_in[14];
    const float* lin1_b  = (const float*)d_in[15];
    const float* lin2_w  = (const float*)d_in[16];
    const float* lin2_b  = (const float*)d_in[17];
    float* out = (float*)d_out;

    float* h     = (float*)d_ws;                 // N*32
    float* agg   = h + (size_t)N_NODES * 32;     // N*32 (z written in-place)
    float* stats = agg + (size_t)N_NODES * 32;   // 64 (contiguous after agg)
    float* gsum  = stats + 64;                   // G*32
    float* gcnt  = gsum + (size_t)N_GRAPHS * 32; // G (contiguous after gsum)

    int nb_nodes = (N_NODES + 255) / 256;
    int nb_edges = (N_EDGES + 255) / 256;
    int nb_vec   = (N_NODES * 8 + 255) / 256;

    k_encode<<<nb_nodes, 256, 0, stream>>>(x, node_w, node_b, h);
    for (int l = 0; l < 2; l++) {
        hipMemsetAsync(agg, 0, ((size_t)N_NODES * 32 + 64) * sizeof(float), stream);
        k_edge<<<nb_edges, 256, 0, stream>>>(ei, eattr, edge_w, edge_b, h, agg);
        k_update<<<nb_nodes, 256, 0, stream>>>(h, agg, conv_w1 + l * 2400, conv_b1 + l * 75,
                                               conv_w2 + l * 2400, conv_b2 + l * 32, stats);
        k_bn<<<nb_vec, 256, 0, stream>>>(agg, h, stats, bn_g + l * 32, bn_b + l * 32);
    }
    hipMemsetAsync(gsum, 0, ((size_t)N_GRAPHS * 32 + N_GRAPHS) * sizeof(float), stream);
    k_pool<<<nb_vec, 256, 0, stream>>>(h, batch, gsum, gcnt);
    k_head<<<(N_GRAPHS + 255) / 256, 256, 0, stream>>>(gsum, gcnt, lin1_w, lin1_b, lin2_w, lin2_b, out);
}

// Round 2
// 1755.488 us; speedup vs baseline: 6.7982x; 6.7982x over previous
//
#include <hip/hip_runtime.h>

#define N_NODES 100000
#define N_EDGES 3200000
#define N_GRAPHS 5000
#define BN_EPS 1e-5f
#define NPAD 100096  // 391 * 256

// ---------- node encoder: h = x @ node_w + node_b   [N,14]@[14,32] ----------
__global__ void k_encode(const float* __restrict__ x, const float* __restrict__ W,
                         const float* __restrict__ b, float* __restrict__ h) {
    __shared__ float sW[448];
    __shared__ float sb[32];
    for (int i = threadIdx.x; i < 448; i += 256) sW[i] = W[i];
    if (threadIdx.x < 32) sb[threadIdx.x] = b[threadIdx.x];
    __syncthreads();
    int n = blockIdx.x * 256 + threadIdx.x;
    if (n >= N_NODES) return;
    float xi[14];
#pragma unroll
    for (int k = 0; k < 14; k++) xi[k] = x[n * 14 + k];
    float4* hp = (float4*)(h + (size_t)n * 32);
#pragma unroll
    for (int q = 0; q < 8; q++) {
        float4 acc;
        float* ap = (float*)&acc;
#pragma unroll
        for (int i = 0; i < 4; i++) {
            int c = q * 4 + i;
            float a = sb[c];
#pragma unroll
            for (int k = 0; k < 14; k++) a += xi[k] * sW[k * 32 + c];
            ap[i] = a;
        }
        hp[q] = acc;
    }
}

// ---------- CSR build (once per call; dst is layer-invariant) ----------
__global__ void k_hist(const int* __restrict__ ei, int* __restrict__ cnt) {
    int e = blockIdx.x * 256 + threadIdx.x;
    if (e >= N_EDGES) return;
    atomicAdd(&cnt[ei[N_EDGES + e]], 1);
}

__global__ void k_scan1(const int* __restrict__ cnt, int* __restrict__ bsum) {
    __shared__ int s[256];
    int i = blockIdx.x * 256 + threadIdx.x;
    s[threadIdx.x] = cnt[i];
    __syncthreads();
    for (int off = 128; off > 0; off >>= 1) {
        if (threadIdx.x < off) s[threadIdx.x] += s[threadIdx.x + off];
        __syncthreads();
    }
    if (threadIdx.x == 0) bsum[blockIdx.x] = s[0];
}

__global__ void k_scan2(const int* __restrict__ bsum, int* __restrict__ boff) {
    if (threadIdx.x == 0 && blockIdx.x == 0) {
        int acc = 0;
        for (int i = 0; i < NPAD / 256; i++) { boff[i] = acc; acc += bsum[i]; }
    }
}

__global__ void k_scan3(const int* __restrict__ cnt, const int* __restrict__ boff,
                        int* __restrict__ offs, int* __restrict__ cursor) {
    __shared__ int s[256];
    int i = blockIdx.x * 256 + threadIdx.x;
    int v = cnt[i];
    s[threadIdx.x] = v;
    __syncthreads();
#pragma unroll
    for (int off = 1; off < 256; off <<= 1) {
        int add = (threadIdx.x >= off) ? s[threadIdx.x - off] : 0;
        __syncthreads();
        s[threadIdx.x] += add;
        __syncthreads();
    }
    int excl = s[threadIdx.x] - v + boff[blockIdx.x];
    offs[i] = excl;
    cursor[i] = excl;
    if (i == NPAD - 1) offs[NPAD] = excl + v;
}

// packed[j] = (ea0, ea1, ea2, src_as_float) sorted by dst
__global__ void k_scatter(const int* __restrict__ ei, const float* __restrict__ ea,
                          int* __restrict__ cursor, float4* __restrict__ packed) {
    int e = blockIdx.x * 256 + threadIdx.x;
    if (e >= N_EDGES) return;
    int src = ei[e];
    int dst = ei[N_EDGES + e];
    float a0 = ea[(size_t)e * 3 + 0], a1 = ea[(size_t)e * 3 + 1], a2 = ea[(size_t)e * 3 + 2];
    int j = atomicAdd(&cursor[dst], 1);
    packed[j] = make_float4(a0, a1, a2, __int_as_float(src));
}

// ---------- pull aggregation: agg[n] = sum_j relu(h[src_j] + ea_j@eW + eb), no atomics ----------
__global__ void __launch_bounds__(256) k_agg(const float4* __restrict__ packed,
                                             const int* __restrict__ offs,
                                             const float* __restrict__ eW, const float* __restrict__ eb,
                                             const float* __restrict__ h, float* __restrict__ agg) {
    int t = blockIdx.x * 256 + threadIdx.x;   // exactly 800000 threads
    int n = t >> 3, q = t & 7;
    int c0 = q * 4;
    float w0[4], w1[4], w2[4], bb[4];
#pragma unroll
    for (int i = 0; i < 4; i++) {
        w0[i] = eW[c0 + i];
        w1[i] = eW[32 + c0 + i];
        w2[i] = eW[64 + c0 + i];
        bb[i] = eb[c0 + i];
    }
    int beg = offs[n], end = offs[n + 1];
    float acc[4] = {0.f, 0.f, 0.f, 0.f};
    for (int j = beg; j < end; j++) {
        float4 p = packed[j];
        int src = __float_as_int(p.w);
        float4 hs = *(const float4*)(h + (size_t)src * 32 + c0);
        const float* hp = (const float*)&hs;
#pragma unroll
        for (int i = 0; i < 4; i++) {
            float m = hp[i] + p.x * w0[i] + p.y * w1[i] + p.z * w2[i] + bb[i];
            acc[i] += fmaxf(m, 0.f);
        }
    }
    float4 o = make_float4(acc[0], acc[1], acc[2], acc[3]);
    *(float4*)(agg + (size_t)n * 32 + c0) = o;
}

// ---------- z = relu((h+agg)@W1+b1)@W2+b2, in-place over agg; per-channel sum/sumsq ----------
__global__ void __launch_bounds__(256) k_update(const float* __restrict__ h, float* __restrict__ zio,
                                                const float* __restrict__ W1, const float* __restrict__ b1,
                                                const float* __restrict__ W2, const float* __restrict__ b2,
                                                float* __restrict__ stats) {
    __shared__ float sW1[2400], sW2[2400], sb1[75], sb2[32];
    for (int i = threadIdx.x; i < 2400; i += 256) { sW1[i] = W1[i]; sW2[i] = W2[i]; }
    if (threadIdx.x < 75) sb1[threadIdx.x] = b1[threadIdx.x];
    if (threadIdx.x < 32) sb2[threadIdx.x] = b2[threadIdx.x];
    __syncthreads();
    int n = blockIdx.x * 256 + threadIdx.x;
    bool valid = n < N_NODES;
    float zin[32];
    if (valid) {
#pragma unroll
        for (int c = 0; c < 32; c++) zin[c] = h[(size_t)n * 32 + c] + zio[(size_t)n * 32 + c];
    } else {
#pragma unroll
        for (int c = 0; c < 32; c++) zin[c] = 0.f;
    }
    float hid[75];
#pragma unroll
    for (int j = 0; j < 75; j++) hid[j] = sb1[j];
    for (int c = 0; c < 32; c++) {
        float zc = zin[c];
#pragma unroll
        for (int j = 0; j < 75; j++) hid[j] += zc * sW1[c * 75 + j];
    }
#pragma unroll
    for (int j = 0; j < 75; j++) hid[j] = fmaxf(hid[j], 0.f);
    float zo[32];
#pragma unroll
    for (int c = 0; c < 32; c++) zo[c] = sb2[c];
    for (int j = 0; j < 75; j++) {
        float hj = hid[j];
#pragma unroll
        for (int c = 0; c < 32; c++) zo[c] += hj * sW2[j * 32 + c];
    }
    if (valid) {
#pragma unroll
        for (int c = 0; c < 32; c++) zio[(size_t)n * 32 + c] = zo[c];
    }
    int lane = threadIdx.x & 63;
#pragma unroll
    for (int c = 0; c < 32; c++) {
        float s = valid ? zo[c] : 0.f;
        float s2 = valid ? zo[c] * zo[c] : 0.f;
#pragma unroll
        for (int off = 32; off > 0; off >>= 1) {
            s += __shfl_down(s, off, 64);
            s2 += __shfl_down(s2, off, 64);
        }
        if (lane == 0) { atomicAdd(&stats[c], s); atomicAdd(&stats[32 + c], s2); }
    }
}

// ---------- h = relu((z - mu) * g * rsqrt(var+eps) + b) ----------
__global__ void k_bn(const float* __restrict__ z, float* __restrict__ h,
                     const float* __restrict__ stats, const float* __restrict__ g,
                     const float* __restrict__ b) {
    int t = blockIdx.x * 256 + threadIdx.x;
    if (t >= N_NODES * 8) return;
    int q = t & 7;
    float4 zv = ((const float4*)z)[t];
    float* zp = (float*)&zv;
    float4 ov;
    float* op = (float*)&ov;
    const float invN = 1.0f / (float)N_NODES;
#pragma unroll
    for (int i = 0; i < 4; i++) {
        int c = q * 4 + i;
        float mu = stats[c] * invN;
        float var = stats[32 + c] * invN - mu * mu;
        float sc = g[c] / sqrtf(var + BN_EPS);
        float val = (zp[i] - mu) * sc + b[c];
        op[i] = fmaxf(val, 0.f);
    }
    ((float4*)h)[t] = ov;
}

__global__ void k_pool(const float* __restrict__ h, const int* __restrict__ batch,
                       float* __restrict__ gsum, float* __restrict__ gcnt) {
    int t = blockIdx.x * 256 + threadIdx.x;
    if (t >= N_NODES * 8) return;
    int n = t >> 3, q = t & 7;
    int g = batch[n];
    float4 hv = ((const float4*)h)[t];
    float* hp = (float*)&hv;
    float* gp = gsum + (size_t)g * 32 + q * 4;
#pragma unroll
    for (int i = 0; i < 4; i++) atomicAdd(gp + i, hp[i]);
    if (q == 0) atomicAdd(&gcnt[g], 1.0f);
}

__global__ void k_head(const float* __restrict__ gsum, const float* __restrict__ gcnt,
                       const float* __restrict__ W1, const float* __restrict__ b1,
                       const float* __restrict__ W2, const float* __restrict__ b2,
                       float* __restrict__ out) {
    __shared__ float sW1[512], sb1[16], sW2[32], sb2[2];
    for (int i = threadIdx.x; i < 512; i += 256) sW1[i] = W1[i];
    if (threadIdx.x < 16) sb1[threadIdx.x] = b1[threadIdx.x];
    if (threadIdx.x < 32) sW2[threadIdx.x] = W2[threadIdx.x];
    if (threadIdx.x < 2) sb2[threadIdx.x] = b2[threadIdx.x];
    __syncthreads();
    int gI = blockIdx.x * 256 + threadIdx.x;
    if (gI >= N_GRAPHS) return;
    float cnt = fmaxf(gcnt[gI], 1.0f);
    float inv = 1.0f / cnt;
    float gx[32];
#pragma unroll
    for (int c = 0; c < 32; c++) gx[c] = gsum[(size_t)gI * 32 + c] * inv;
    float hid[16];
#pragma unroll
    for (int j = 0; j < 16; j++) {
        float a = sb1[j];
#pragma unroll
        for (int c = 0; c < 32; c++) a += gx[c] * sW1[c * 16 + j];
        hid[j] = fmaxf(a, 0.f);
    }
#pragma unroll
    for (int o = 0; o < 2; o++) {
        float a = sb2[o];
#pragma unroll
        for (int j = 0; j < 16; j++) a += hid[j] * sW2[j * 2 + o];
        out[(size_t)gI * 2 + o] = a;
    }
}

extern "C" void kernel_launch(void* const* d_in, const int* in_sizes, int n_in,
                              void* d_out, int out_size, void* d_ws, size_t ws_size,
                              hipStream_t stream) {
    const float* x       = (const float*)d_in[0];
    const int*   ei      = (const int*)d_in[1];
    const float* eattr   = (const float*)d_in[2];
    const int*   batch   = (const int*)d_in[3];
    const float* node_w  = (const float*)d_in[4];
    const float* node_b  = (const float*)d_in[5];
    const float* edge_w  = (const float*)d_in[6];
    const float* edge_b  = (const float*)d_in[7];
    const float* conv_w1 = (const float*)d_in[8];
    const float* conv_b1 = (const float*)d_in[9];
    const float* conv_w2 = (const float*)d_in[10];
    const float* conv_b2 = (const float*)d_in[11];
    const float* bn_g    = (const float*)d_in[12];
    const float* bn_b    = (const float*)d_in[13];
    const float* lin1_w  = (const float*)d_in[14];
    const float* lin1_b  = (const float*)d_in[15];
    const float* lin2_w  = (const float*)d_in[16];
    const float* lin2_b  = (const float*)d_in[17];
    float* out = (float*)d_out;

    // workspace layout (packed first for 16B alignment)
    float4* packed = (float4*)d_ws;                        // E float4 = 51.2 MB
    float*  h      = (float*)(packed + N_EDGES);           // N*32
    float*  agg    = h + (size_t)N_NODES * 32;             // N*32 (z in-place)
    int*    cnt    = (int*)(agg + (size_t)N_NODES * 32);   // NPAD
    int*    offs   = cnt + NPAD;                           // NPAD+1
    int*    cursor = offs + NPAD + 1;                      // NPAD
    int*    bsum   = cursor + NPAD;                        // NPAD/256
    int*    boff   = bsum + NPAD / 256;                    // NPAD/256
    float*  stats  = (float*)(boff + NPAD / 256);          // 64
    float*  gsum   = stats + 64;                           // G*32
    float*  gcnt   = gsum + (size_t)N_GRAPHS * 32;         // G

    int nb_nodes = (N_NODES + 255) / 256;
    int nb_edges = (N_EDGES + 255) / 256;
    int nb_vec   = (N_NODES * 8 + 255) / 256;
    int nb_scan  = NPAD / 256;                             // 391

    hipMemsetAsync(cnt, 0, NPAD * sizeof(int), stream);
    k_encode<<<nb_nodes, 256, 0, stream>>>(x, node_w, node_b, h);
    k_hist<<<nb_edges, 256, 0, stream>>>(ei, cnt);
    k_scan1<<<nb_scan, 256, 0, stream>>>(cnt, bsum);
    k_scan2<<<1, 64, 0, stream>>>(bsum, boff);
    k_scan3<<<nb_scan, 256, 0, stream>>>(cnt, boff, offs, cursor);
    k_scatter<<<nb_edges, 256, 0, stream>>>(ei, eattr, cursor, packed);

    for (int l = 0; l < 2; l++) {
        hipMemsetAsync(stats, 0, 64 * sizeof(float), stream);
        k_agg<<<N_NODES * 8 / 256, 256, 0, stream>>>(packed, offs, edge_w, edge_b, h, agg);
        k_update<<<nb_nodes, 256, 0, stream>>>(h, agg, conv_w1 + l * 2400, conv_b1 + l * 75,
                                               conv_w2 + l * 2400, conv_b2 + l * 32, stats);
        k_bn<<<nb_vec, 256, 0, stream>>>(agg, h, stats, bn_g + l * 32, bn_b + l * 32);
    }
    hipMemsetAsync(gsum, 0, ((size_t)N_GRAPHS * 32 + N_GRAPHS) * sizeof(float), stream);
    k_pool<<<nb_vec, 256, 0, stream>>>(h, batch, gsum, gcnt);
    k_head<<<(N_GRAPHS + 255) / 256, 256, 0, stream>>>(gsum, gcnt, lin1_w, lin1_b, lin2_w, lin2_b, out);
}

// Round 3
// 1754.334 us; speedup vs baseline: 6.8026x; 1.0007x over previous
//
#include <hip/hip_runtime.h>

#define N_NODES 100000
#define N_EDGES 3200000
#define N_GRAPHS 5000
#define BN_EPS 1e-5f
#define NPAD 100096  // 391 * 256

// ---------- node encoder: h = x @ node_w + node_b   [N,14]@[14,32] ----------
__global__ void k_encode(const float* __restrict__ x, const float* __restrict__ W,
                         const float* __restrict__ b, float* __restrict__ h) {
    __shared__ float sW[448];
    __shared__ float sb[32];
    for (int i = threadIdx.x; i < 448; i += 256) sW[i] = W[i];
    if (threadIdx.x < 32) sb[threadIdx.x] = b[threadIdx.x];
    __syncthreads();
    int n = blockIdx.x * 256 + threadIdx.x;
    if (n >= N_NODES) return;
    float xi[14];
#pragma unroll
    for (int k = 0; k < 14; k++) xi[k] = x[n * 14 + k];
    float4* hp = (float4*)(h + (size_t)n * 32);
#pragma unroll
    for (int q = 0; q < 8; q++) {
        float4 acc;
        float* ap = (float*)&acc;
#pragma unroll
        for (int i = 0; i < 4; i++) {
            int c = q * 4 + i;
            float a = sb[c];
#pragma unroll
            for (int k = 0; k < 14; k++) a += xi[k] * sW[k * 32 + c];
            ap[i] = a;
        }
        hp[q] = acc;
    }
}

// ---------- CSR build (once per call; dst is layer-invariant) ----------
__global__ void k_hist(const int* __restrict__ ei, int* __restrict__ cnt) {
    int e = blockIdx.x * 256 + threadIdx.x;
    if (e >= N_EDGES) return;
    atomicAdd(&cnt[ei[N_EDGES + e]], 1);
}

__global__ void k_scan1(const int* __restrict__ cnt, int* __restrict__ bsum) {
    __shared__ int s[256];
    int i = blockIdx.x * 256 + threadIdx.x;
    s[threadIdx.x] = cnt[i];
    __syncthreads();
    for (int off = 128; off > 0; off >>= 1) {
        if (threadIdx.x < off) s[threadIdx.x] += s[threadIdx.x + off];
        __syncthreads();
    }
    if (threadIdx.x == 0) bsum[blockIdx.x] = s[0];
}

__global__ void k_scan2(const int* __restrict__ bsum, int* __restrict__ boff) {
    if (threadIdx.x == 0 && blockIdx.x == 0) {
        int acc = 0;
        for (int i = 0; i < NPAD / 256; i++) { boff[i] = acc; acc += bsum[i]; }
    }
}

__global__ void k_scan3(const int* __restrict__ cnt, const int* __restrict__ boff,
                        int* __restrict__ offs, int* __restrict__ cursor) {
    __shared__ int s[256];
    int i = blockIdx.x * 256 + threadIdx.x;
    int v = cnt[i];
    s[threadIdx.x] = v;
    __syncthreads();
#pragma unroll
    for (int off = 1; off < 256; off <<= 1) {
        int add = (threadIdx.x >= off) ? s[threadIdx.x - off] : 0;
        __syncthreads();
        s[threadIdx.x] += add;
        __syncthreads();
    }
    int excl = s[threadIdx.x] - v + boff[blockIdx.x];
    offs[i] = excl;
    cursor[i] = excl;
    if (i == NPAD - 1) offs[NPAD] = excl + v;
}

// packed[j] = (ea0, ea1, ea2, src_as_float) sorted by dst
__global__ void k_scatter(const int* __restrict__ ei, const float* __restrict__ ea,
                          int* __restrict__ cursor, float4* __restrict__ packed) {
    int e = blockIdx.x * 256 + threadIdx.x;
    if (e >= N_EDGES) return;
    int src = ei[e];
    int dst = ei[N_EDGES + e];
    float a0 = ea[(size_t)e * 3 + 0], a1 = ea[(size_t)e * 3 + 1], a2 = ea[(size_t)e * 3 + 2];
    int j = atomicAdd(&cursor[dst], 1);
    packed[j] = make_float4(a0, a1, a2, __int_as_float(src));
}

// ---------- pull aggregation: agg[n] = sum_j relu(h[src_j] + ea_j@eW + eb), no atomics ----------
__global__ void __launch_bounds__(256) k_agg(const float4* __restrict__ packed,
                                             const int* __restrict__ offs,
                                             const float* __restrict__ eW, const float* __restrict__ eb,
                                             const float* __restrict__ h, float* __restrict__ agg) {
    int t = blockIdx.x * 256 + threadIdx.x;   // exactly 800768 threads
    int n = t >> 3, q = t & 7;
    if (n >= N_NODES) return;
    int c0 = q * 4;
    float w0[4], w1[4], w2[4], bb[4];
#pragma unroll
    for (int i = 0; i < 4; i++) {
        w0[i] = eW[c0 + i];
        w1[i] = eW[32 + c0 + i];
        w2[i] = eW[64 + c0 + i];
        bb[i] = eb[c0 + i];
    }
    int beg = offs[n], end = offs[n + 1];
    float acc[4] = {0.f, 0.f, 0.f, 0.f};
    for (int j = beg; j < end; j++) {
        float4 p = packed[j];
        int src = __float_as_int(p.w);
        float4 hs = *(const float4*)(h + (size_t)src * 32 + c0);
        const float* hp = (const float*)&hs;
#pragma unroll
        for (int i = 0; i < 4; i++) {
            float m = hp[i] + p.x * w0[i] + p.y * w1[i] + p.z * w2[i] + bb[i];
            acc[i] += fmaxf(m, 0.f);
        }
    }
    float4 o = make_float4(acc[0], acc[1], acc[2], acc[3]);
    *(float4*)(agg + (size_t)n * 32 + c0) = o;
}

// ---------- z = relu((h+agg)@W1+b1)@W2+b2, in-place over agg; per-channel sum/sumsq ----------
// All register arrays constant-indexed (loops touching them fully unrolled) to avoid scratch spill.
// W1 staged in LDS with rows padded to 76 floats (16B-aligned) for ds_read_b128.
__global__ void __launch_bounds__(256) k_update(const float* __restrict__ h, float* __restrict__ zio,
                                                const float* __restrict__ W1, const float* __restrict__ b1,
                                                const float* __restrict__ W2, const float* __restrict__ b2,
                                                float* __restrict__ stats) {
    __shared__ float sW1[32 * 76];   // sW1[c*76 + j]
    __shared__ float sW2[75 * 32];   // sW2[j*32 + c]
    __shared__ float sb1[75], sb2[32];
    for (int i = threadIdx.x; i < 2400; i += 256) {
        int c = i / 75, j = i % 75;
        sW1[c * 76 + j] = W1[i];
        sW2[i] = W2[i];
    }
    if (threadIdx.x < 75) sb1[threadIdx.x] = b1[threadIdx.x];
    if (threadIdx.x < 32) sb2[threadIdx.x] = b2[threadIdx.x];
    __syncthreads();
    int n = blockIdx.x * 256 + threadIdx.x;
    bool valid = n < N_NODES;
    const size_t base = (size_t)(valid ? n : 0) * 32;

    // GEMM1: hid = relu(z @ W1 + b1), hid[75] register-resident
    float hid[75];
#pragma unroll
    for (int j = 0; j < 75; j++) hid[j] = sb1[j];
#pragma unroll 2
    for (int c4 = 0; c4 < 8; c4++) {
        float4 hv = *(const float4*)(h + base + c4 * 4);
        float4 av = *(const float4*)(zio + base + c4 * 4);
        float zc[4];
        zc[0] = hv.x + av.x; zc[1] = hv.y + av.y; zc[2] = hv.z + av.z; zc[3] = hv.w + av.w;
#pragma unroll
        for (int i = 0; i < 4; i++) {
            const float* wrow = &sW1[(c4 * 4 + i) * 76];
#pragma unroll
            for (int j = 0; j < 75; j++) hid[j] += zc[i] * wrow[j];
        }
    }
#pragma unroll
    for (int j = 0; j < 75; j++) hid[j] = fmaxf(hid[j], 0.f);

    // GEMM2: zo = hid @ W2 + b2, fully unrolled so zo[32] and hid[75] stay in registers
    float zo[32];
#pragma unroll
    for (int c = 0; c < 32; c++) zo[c] = sb2[c];
#pragma unroll
    for (int j = 0; j < 75; j++) {
        float hj = hid[j];
        const float* wrow = &sW2[j * 32];
#pragma unroll
        for (int c = 0; c < 32; c++) zo[c] += hj * wrow[c];
    }
    if (valid) {
#pragma unroll
        for (int q = 0; q < 8; q++) {
            float4 o = make_float4(zo[q * 4], zo[q * 4 + 1], zo[q * 4 + 2], zo[q * 4 + 3]);
            *(float4*)(zio + base + q * 4) = o;
        }
    }

    // per-channel sum / sumsq for BN
    int lane = threadIdx.x & 63;
#pragma unroll
    for (int c = 0; c < 32; c++) {
        float s = valid ? zo[c] : 0.f;
        float s2 = valid ? zo[c] * zo[c] : 0.f;
#pragma unroll
        for (int off = 32; off > 0; off >>= 1) {
            s += __shfl_down(s, off, 64);
            s2 += __shfl_down(s2, off, 64);
        }
        if (lane == 0) { atomicAdd(&stats[c], s); atomicAdd(&stats[32 + c], s2); }
    }
}

// ---------- h = relu((z - mu) * g * rsqrt(var+eps) + b) ----------
__global__ void k_bn(const float* __restrict__ z, float* __restrict__ h,
                     const float* __restrict__ stats, const float* __restrict__ g,
                     const float* __restrict__ b) {
    int t = blockIdx.x * 256 + threadIdx.x;
    if (t >= N_NODES * 8) return;
    int q = t & 7;
    float4 zv = ((const float4*)z)[t];
    float* zp = (float*)&zv;
    float4 ov;
    float* op = (float*)&ov;
    const float invN = 1.0f / (float)N_NODES;
#pragma unroll
    for (int i = 0; i < 4; i++) {
        int c = q * 4 + i;
        float mu = stats[c] * invN;
        float var = stats[32 + c] * invN - mu * mu;
        float sc = g[c] / sqrtf(var + BN_EPS);
        float val = (zp[i] - mu) * sc + b[c];
        op[i] = fmaxf(val, 0.f);
    }
    ((float4*)h)[t] = ov;
}

__global__ void k_pool(const float* __restrict__ h, const int* __restrict__ batch,
                       float* __restrict__ gsum, float* __restrict__ gcnt) {
    int t = blockIdx.x * 256 + threadIdx.x;
    if (t >= N_NODES * 8) return;
    int n = t >> 3, q = t & 7;
    int g = batch[n];
    float4 hv = ((const float4*)h)[t];
    float* hp = (float*)&hv;
    float* gp = gsum + (size_t)g * 32 + q * 4;
#pragma unroll
    for (int i = 0; i < 4; i++) atomicAdd(gp + i, hp[i]);
    if (q == 0) atomicAdd(&gcnt[g], 1.0f);
}

__global__ void k_head(const float* __restrict__ gsum, const float* __restrict__ gcnt,
                       const float* __restrict__ W1, const float* __restrict__ b1,
                       const float* __restrict__ W2, const float* __restrict__ b2,
                       float* __restrict__ out) {
    __shared__ float sW1[512], sb1[16], sW2[32], sb2[2];
    for (int i = threadIdx.x; i < 512; i += 256) sW1[i] = W1[i];
    if (threadIdx.x < 16) sb1[threadIdx.x] = b1[threadIdx.x];
    if (threadIdx.x < 32) sW2[threadIdx.x] = W2[threadIdx.x];
    if (threadIdx.x < 2) sb2[threadIdx.x] = b2[threadIdx.x];
    __syncthreads();
    int gI = blockIdx.x * 256 + threadIdx.x;
    if (gI >= N_GRAPHS) return;
    float cnt = fmaxf(gcnt[gI], 1.0f);
    float inv = 1.0f / cnt;
    float gx[32];
#pragma unroll
    for (int c = 0; c < 32; c++) gx[c] = gsum[(size_t)gI * 32 + c] * inv;
    float hid[16];
#pragma unroll
    for (int j = 0; j < 16; j++) {
        float a = sb1[j];
#pragma unroll
        for (int c = 0; c < 32; c++) a += gx[c] * sW1[c * 16 + j];
        hid[j] = fmaxf(a, 0.f);
    }
#pragma unroll
    for (int o = 0; o < 2; o++) {
        float a = sb2[o];
#pragma unroll
        for (int j = 0; j < 16; j++) a += hid[j] * sW2[j * 2 + o];
        out[(size_t)gI * 2 + o] = a;
    }
}

extern "C" void kernel_launch(void* const* d_in, const int* in_sizes, int n_in,
                              void* d_out, int out_size, void* d_ws, size_t ws_size,
                              hipStream_t stream) {
    const float* x       = (const float*)d_in[0];
    const int*   ei      = (const int*)d_in[1];
    const float* eattr   = (const float*)d_in[2];
    const int*   batch   = (const int*)d_in[3];
    const float* node_w  = (const float*)d_in[4];
    const float* node_b  = (const float*)d_in[5];
    const float* edge_w  = (const float*)d_in[6];
    const float* edge_b  = (const float*)d_in[7];
    const float* conv_w1 = (const float*)d_in[8];
    const float* conv_b1 = (const float*)d_in[9];
    const float* conv_w2 = (const float*)d_in[10];
    const float* conv_b2 = (const float*)d_in[11];
    const float* bn_g    = (const float*)d_in[12];
    const float* bn_b    = (const float*)d_in[13];
    const float* lin1_w  = (const float*)d_in[14];
    const float* lin1_b  = (const float*)d_in[15];
    const float* lin2_w  = (const float*)d_in[16];
    const float* lin2_b  = (const float*)d_in[17];
    float* out = (float*)d_out;

    // workspace layout (packed first for 16B alignment)
    float4* packed = (float4*)d_ws;                        // E float4 = 51.2 MB
    float*  h      = (float*)(packed + N_EDGES);           // N*32
    float*  agg    = h + (size_t)N_NODES * 32;             // N*32 (z in-place)
    int*    cnt    = (int*)(agg + (size_t)N_NODES * 32);   // NPAD
    int*    offs   = cnt + NPAD;                           // NPAD+1
    int*    cursor = offs + NPAD + 1;                      // NPAD
    int*    bsum   = cursor + NPAD;                        // NPAD/256
    int*    boff   = bsum + NPAD / 256;                    // NPAD/256
    float*  stats  = (float*)(boff + NPAD / 256);          // 64
    float*  gsum   = stats + 64;                           // G*32
    float*  gcnt   = gsum + (size_t)N_GRAPHS * 32;         // G

    int nb_nodes = (N_NODES + 255) / 256;
    int nb_edges = (N_EDGES + 255) / 256;
    int nb_vec   = (N_NODES * 8 + 255) / 256;
    int nb_scan  = NPAD / 256;                             // 391

    hipMemsetAsync(cnt, 0, NPAD * sizeof(int), stream);
    k_encode<<<nb_nodes, 256, 0, stream>>>(x, node_w, node_b, h);
    k_hist<<<nb_edges, 256, 0, stream>>>(ei, cnt);
    k_scan1<<<nb_scan, 256, 0, stream>>>(cnt, bsum);
    k_scan2<<<1, 64, 0, stream>>>(bsum, boff);
    k_scan3<<<nb_scan, 256, 0, stream>>>(cnt, boff, offs, cursor);
    k_scatter<<<nb_edges, 256, 0, stream>>>(ei, eattr, cursor, packed);

    for (int l = 0; l < 2; l++) {
        hipMemsetAsync(stats, 0, 64 * sizeof(float), stream);
        k_agg<<<NPAD * 8 / 256, 256, 0, stream>>>(packed, offs, edge_w, edge_b, h, agg);
        k_update<<<nb_nodes, 256, 0, stream>>>(h, agg, conv_w1 + l * 2400, conv_b1 + l * 75,
                                               conv_w2 + l * 2400, conv_b2 + l * 32, stats);
        k_bn<<<nb_vec, 256, 0, stream>>>(agg, h, stats, bn_g + l * 32, bn_b + l * 32);
    }
    hipMemsetAsync(gsum, 0, ((size_t)N_GRAPHS * 32 + N_GRAPHS) * sizeof(float), stream);
    k_pool<<<nb_vec, 256, 0, stream>>>(h, batch, gsum, gcnt);
    k_head<<<(N_GRAPHS + 255) / 256, 256, 0, stream>>>(gsum, gcnt, lin1_w, lin1_b, lin2_w, lin2_b, out);
}